// Round 1
// baseline (2136.521 us; speedup 1.0000x reference)
//
#include <hip/hip_runtime.h>

#define NSV 20
#define SS  1000

typedef __bf16 bf16_t;
typedef __bf16 bf16x8 __attribute__((ext_vector_type(8)));
typedef float  f32x4  __attribute__((ext_vector_type(4)));

__device__ __forceinline__ float selu_f(float v) {
    const float scale = 1.0507009873554805f;
    const float alpha = 1.6732632423543772f;
    return v > 0.f ? scale * v : scale * alpha * expm1f(v);
}

// ---------------------------------------------------------------------------
// RNN kernel: one block per batch row, 256 threads.
// Thread pair (2j, 2j+1) computes hidden unit j; each holds half the weight
// row in registers (64 fp32). Combine halves with __shfl_xor(1).
// ---------------------------------------------------------------------------
__global__ __launch_bounds__(256, 1) void rnn_kernel(
    const float* __restrict__ x,
    const float* __restrict__ gw0, const float* __restrict__ gb0,
    const float* __restrict__ gw1, const float* __restrict__ gb1,
    const float* __restrict__ gw2, const float* __restrict__ gb2,
    const float* __restrict__ gw3, const float* __restrict__ gb3,
    float* __restrict__ statevar)
{
    const int b    = blockIdx.x;
    const int tid  = threadIdx.x;
    const int j    = tid >> 1;
    const int half = tid & 1;

    __shared__ float sv[NSV];
    __shared__ __align__(16) float h0buf[32];
    __shared__ __align__(16) float hA[128];
    __shared__ __align__(16) float hB[128];
    __shared__ float sdt;

    // ---- weights into registers ----
    float w0[13], w1[64], w2[64], w3[64];
#pragma unroll
    for (int i = 0; i < 13; ++i) w0[i] = gw0[j * 26 + half * 13 + i];
#pragma unroll
    for (int i = 0; i < 64; ++i) w1[i] = gw1[j * 128 + half * 64 + i];
#pragma unroll
    for (int i = 0; i < 64; ++i) w2[i] = gw2[j * 128 + half * 64 + i];
    if (tid < 2 * NSV) {
#pragma unroll
        for (int i = 0; i < 64; ++i) w3[i] = gw3[j * 128 + half * 64 + i];
    }
    const float b0 = gb0[j];
    const float b1 = gb1[j];
    const float b2 = gb2[j];
    const float b3 = (tid < 2 * NSV) ? gb3[j] : 0.f;

    if (tid < NSV) {
        sv[tid] = 0.f;
        statevar[b * (SS * NSV) + tid] = 0.f;   // statevar[b][0][:] = sv0 = 0
    }
    __syncthreads();

    const float* xb = x + b * (SS * 13);

#define DOT64(W, HPTR, OUT) do {                                   \
        const float4* h4_ = (const float4*)(HPTR);                 \
        float s0_ = 0.f, s1_ = 0.f, s2_ = 0.f, s3_ = 0.f;          \
        _Pragma("unroll")                                          \
        for (int i_ = 0; i_ < 16; ++i_) {                          \
            float4 hv_ = h4_[i_];                                  \
            s0_ = fmaf(W[4*i_+0], hv_.x, s0_);                     \
            s1_ = fmaf(W[4*i_+1], hv_.y, s1_);                     \
            s2_ = fmaf(W[4*i_+2], hv_.z, s2_);                     \
            s3_ = fmaf(W[4*i_+3], hv_.w, s3_);                     \
        }                                                          \
        OUT = (s0_ + s1_) + (s2_ + s3_);                           \
    } while (0)

    for (int t = 0; t < SS - 1; ++t) {
        // build h0 = [eps(6), sv(20)], and dt
        if (tid < 6)        h0buf[tid] = xb[t * 13 + 1 + tid];
        else if (tid < 26)  h0buf[tid] = sv[tid - 6];
        if (tid == 32)      sdt = xb[(t + 1) * 13] - xb[t * 13];
        __syncthreads();

        // L0: 26 -> 128
        {
            const float* hh = &h0buf[half * 13];
            float s0 = 0.f, s1 = 0.f, s2 = 0.f, s3 = 0.f;
#pragma unroll
            for (int i = 0; i < 12; i += 4) {
                s0 = fmaf(w0[i + 0], hh[i + 0], s0);
                s1 = fmaf(w0[i + 1], hh[i + 1], s1);
                s2 = fmaf(w0[i + 2], hh[i + 2], s2);
                s3 = fmaf(w0[i + 3], hh[i + 3], s3);
            }
            s0 = fmaf(w0[12], hh[12], s0);
            float s = (s0 + s1) + (s2 + s3);
            s += __shfl_xor(s, 1, 64);
            if (half == 0) hA[j] = selu_f(s + b0);
        }
        __syncthreads();

        // L1: 128 -> 128   (hA -> hB)
        {
            float s;
            DOT64(w1, &hA[half * 64], s);
            s += __shfl_xor(s, 1, 64);
            if (half == 0) hB[j] = selu_f(s + b1);
        }
        __syncthreads();

        // L2: 128 -> 128   (hB -> hA)
        {
            float s;
            DOT64(w2, &hB[half * 64], s);
            s += __shfl_xor(s, 1, 64);
            if (half == 0) hA[j] = selu_f(s + b2);
        }
        __syncthreads();

        // L3: 128 -> 20, integrate sv
        if (tid < 2 * NSV) {
            float s;
            DOT64(w3, &hA[half * 64], s);
            s += __shfl_xor(s, 1, 64);
            if (half == 0) {
                float svd = s + b3;
                float ns  = sv[j] + sdt * svd;
                sv[j] = ns;
                statevar[b * (SS * NSV) + (t + 1) * NSV + j] = ns;
            }
        }
        __syncthreads();
    }
#undef DOT64
}

// ---------------------------------------------------------------------------
// Weight prep: fp32 -> bf16, pad fw3 from [6][256] to [16][256] with zeros.
// ---------------------------------------------------------------------------
__global__ void prep_weights(
    const float* __restrict__ fw0, const float* __restrict__ fw1,
    const float* __restrict__ fw2, const float* __restrict__ fw3,
    bf16_t* __restrict__ w0b, bf16_t* __restrict__ w1b,
    bf16_t* __restrict__ w2b, bf16_t* __restrict__ w3b)
{
    const int i      = blockIdx.x * blockDim.x + threadIdx.x;
    const int stride = gridDim.x * blockDim.x;
    for (int k = i; k < 256 * 32;  k += stride) w0b[k] = (bf16_t)fw0[k];
    for (int k = i; k < 256 * 256; k += stride) w1b[k] = (bf16_t)fw1[k];
    for (int k = i; k < 256 * 256; k += stride) w2b[k] = (bf16_t)fw2[k];
    for (int k = i; k < 16 * 256;  k += stride) {
        int row = k >> 8, col = k & 255;
        w3b[k] = (row < 6) ? (bf16_t)fw3[row * 256 + col] : (bf16_t)0.f;
    }
}

// ---------------------------------------------------------------------------
// Fused F-MLP: 64-row tiles, bf16 MFMA 16x16x32, fp32 accumulate.
// 4 waves; each wave computes all 64 rows x its 64 output columns.
// Single LDS activation buffer (padded +8 bf16/row -> 2-way max bank alias).
// ---------------------------------------------------------------------------
#define LDA 264   // 256 + 8 pad (row stride 528 B -> 4-bank rotation per row)

template <int K>
__device__ __forceinline__ void mlp_layer(
    bf16_t* __restrict__ A, const bf16_t* __restrict__ Wb,
    const float* __restrict__ bias, int wave, int lane, bool do_selu)
{
    f32x4 acc[4][4];
#pragma unroll
    for (int mt = 0; mt < 4; ++mt)
#pragma unroll
        for (int nt = 0; nt < 4; ++nt) acc[mt][nt] = (f32x4){0.f, 0.f, 0.f, 0.f};

    const int colbase = wave * 64;
    const int mrow = lane & 15;
    const int quad = lane >> 4;

#pragma unroll
    for (int ks = 0; ks < K / 32; ++ks) {
        bf16x8 af[4], bfr[4];
#pragma unroll
        for (int mt = 0; mt < 4; ++mt)
            af[mt] = *(const bf16x8*)&A[(mt * 16 + mrow) * LDA + ks * 32 + quad * 8];
#pragma unroll
        for (int nt = 0; nt < 4; ++nt)
            bfr[nt] = *(const bf16x8*)&Wb[(colbase + nt * 16 + mrow) * K + ks * 32 + quad * 8];
#pragma unroll
        for (int mt = 0; mt < 4; ++mt)
#pragma unroll
            for (int nt = 0; nt < 4; ++nt)
                acc[mt][nt] = __builtin_amdgcn_mfma_f32_16x16x32_bf16(
                    af[mt], bfr[nt], acc[mt][nt], 0, 0, 0);
    }
    __syncthreads();   // all waves done reading A before overwrite

#pragma unroll
    for (int nt = 0; nt < 4; ++nt) {
        const int col = colbase + nt * 16 + mrow;
        const float bv = bias[col];
#pragma unroll
        for (int mt = 0; mt < 4; ++mt) {
#pragma unroll
            for (int rI = 0; rI < 4; ++rI) {
                int row = mt * 16 + quad * 4 + rI;
                float v = acc[mt][nt][rI] + bv;
                if (do_selu) v = selu_f(v);
                A[row * LDA + col] = (bf16_t)v;
            }
        }
    }
    __syncthreads();
}

__global__ __launch_bounds__(256) void fmlp_kernel(
    const float* __restrict__ x, const float* __restrict__ statevar,
    const bf16_t* __restrict__ w0b, const bf16_t* __restrict__ w1b,
    const bf16_t* __restrict__ w2b, const bf16_t* __restrict__ w3b,
    const float* __restrict__ fb0, const float* __restrict__ fb1,
    const float* __restrict__ fb2, const float* __restrict__ fb3,
    float* __restrict__ out)
{
    __shared__ bf16_t A[64 * LDA];

    const int tid  = threadIdx.x;
    const int wave = tid >> 6;
    const int lane = tid & 63;
    const int r0   = blockIdx.x * 64;

    // ---- build input tile: [strain(6), strain_dot(6), statevar(20)] ----
    {
        const int r = tid >> 2;       // 0..63
        const int q = tid & 3;        // 8-col group
        const int g = r0 + r;         // global row = b*1000 + s
        const float* xr  = x + g * 13;
        const float* svr = statevar + g * NSV;
#pragma unroll
        for (int i = 0; i < 8; ++i) {
            int c = q * 8 + i;
            float v = (c < 12) ? xr[c + 1] : svr[c - 12];
            A[r * LDA + c] = (bf16_t)v;
        }
    }
    __syncthreads();

    mlp_layer<32>(A, w0b, fb0, wave, lane, true);
    mlp_layer<256>(A, w1b, fb1, wave, lane, true);
    mlp_layer<256>(A, w2b, fb2, wave, lane, true);

    // ---- L3: 256 -> 6 (padded to N=16), waves split rows ----
    {
        const int mrow = lane & 15;
        const int quad = lane >> 4;
        f32x4 acc = (f32x4){0.f, 0.f, 0.f, 0.f};
#pragma unroll
        for (int ks = 0; ks < 8; ++ks) {
            bf16x8 af  = *(const bf16x8*)&A[(wave * 16 + mrow) * LDA + ks * 32 + quad * 8];
            bf16x8 bfr = *(const bf16x8*)&w3b[mrow * 256 + ks * 32 + quad * 8];
            acc = __builtin_amdgcn_mfma_f32_16x16x32_bf16(af, bfr, acc, 0, 0, 0);
        }
        const int col = mrow;
        if (col < 6) {
            const float bv = fb3[col];
#pragma unroll
            for (int rI = 0; rI < 4; ++rI) {
                int row = wave * 16 + quad * 4 + rI;
                int g = r0 + row;
                out[g * 6 + col] = acc[rI] + bv;
            }
        }
    }
}

// ---------------------------------------------------------------------------
extern "C" void kernel_launch(void* const* d_in, const int* in_sizes, int n_in,
                              void* d_out, int out_size, void* d_ws, size_t ws_size,
                              hipStream_t stream)
{
    const float* x   = (const float*)d_in[0];
    const float* gw0 = (const float*)d_in[1];
    const float* gb0 = (const float*)d_in[2];
    const float* gw1 = (const float*)d_in[3];
    const float* gb1 = (const float*)d_in[4];
    const float* gw2 = (const float*)d_in[5];
    const float* gb2 = (const float*)d_in[6];
    const float* gw3 = (const float*)d_in[7];
    const float* gb3 = (const float*)d_in[8];
    const float* fw0 = (const float*)d_in[9];
    const float* fb0 = (const float*)d_in[10];
    const float* fw1 = (const float*)d_in[11];
    const float* fb1 = (const float*)d_in[12];
    const float* fw2 = (const float*)d_in[13];
    const float* fb2 = (const float*)d_in[14];
    const float* fw3 = (const float*)d_in[15];
    const float* fb3 = (const float*)d_in[16];

    // workspace layout
    float* statevar = (float*)d_ws;                              // 256*1000*20 fp32 = 20,480,000 B
    bf16_t* w0b = (bf16_t*)((char*)d_ws + 20480000);             // 256*32
    bf16_t* w1b = w0b + 256 * 32;                                // 256*256
    bf16_t* w2b = w1b + 256 * 256;                               // 256*256
    bf16_t* w3b = w2b + 256 * 256;                               // 16*256

    prep_weights<<<64, 256, 0, stream>>>(fw0, fw1, fw2, fw3, w0b, w1b, w2b, w3b);
    rnn_kernel<<<256, 256, 0, stream>>>(x, gw0, gb0, gw1, gb1, gw2, gb2, gw3, gb3, statevar);
    fmlp_kernel<<<4000, 256, 0, stream>>>(x, statevar, w0b, w1b, w2b, w3b,
                                          fb0, fb1, fb2, fb3, (float*)d_out);
}